// Round 7
// baseline (223.201 us; speedup 1.0000x reference)
//
#include <hip/hip_runtime.h>
#include <cstdint>
#include <cstddef>

#define Bsz 65536
#define Dsz 256
#define Fsz 512
#define Psz 256

typedef __attribute__((ext_vector_type(8))) short short8;
typedef __attribute__((ext_vector_type(4))) short short4v;
typedef __attribute__((ext_vector_type(4))) float float4v;
typedef __attribute__((ext_vector_type(16))) float float16v;

__device__ inline short f2bf(float f) {
    unsigned u = __builtin_bit_cast(unsigned, f);
    u = (u + 0x7FFFu + ((u >> 16) & 1u)) >> 16;   // RNE
    return (short)u;
}
__device__ inline float bf2f(short s) {
    unsigned u = ((unsigned)(unsigned short)s) << 16;
    return __builtin_bit_cast(float, u);
}

// Fragment-ordered layouts (addresses in shorts):
//   featbB[fc 0..31][kk 0..7][lane 0..63][j 0..7] : featb[f][d],
//       fc=f>>4, kk=d>>5, lane=(f&15)+16*((d>>3)&3), j=d&7
//   pwB/pmB[fc 0..31][ntile 0..7][lane 0..63][j 0..7] : pw[p][f],
//       fc=f>>4, ntile=p>>5, lane=(p&31)+32*((f>>3)&1), j=f&7

// ---------------- k_prep: features -> featbB (fragment order), zero pws_neg ----------------
__global__ void k_prep(const float* __restrict__ features, short* __restrict__ featbB,
                       float* __restrict__ pws_neg) {
    int idx = blockIdx.x * 256 + threadIdx.x;      // 64 blocks * 256 = 16384 = F*D/8
    int f = idx >> 5, d0 = (idx & 31) * 8;
    float4v v0 = *(const float4v*)(features + (size_t)f * Dsz + d0);
    float4v v1 = *(const float4v*)(features + (size_t)f * Dsz + d0 + 4);
    short8 s;
    s[0] = f2bf(v0.x); s[1] = f2bf(v0.y); s[2] = f2bf(v0.z); s[3] = f2bf(v0.w);
    s[4] = f2bf(v1.x); s[5] = f2bf(v1.y); s[6] = f2bf(v1.z); s[7] = f2bf(v1.w);
    int lane = (f & 15) + 16 * ((d0 >> 3) & 3);
    size_t o = (size_t)(f >> 4) * 4096 + (size_t)(d0 >> 5) * 512 + (size_t)lane * 8;
    *(short8*)&featbB[o] = s;
    if (idx < Psz) pws_neg[idx] = 0.f;
}

// ---------------- k_pside: pf = prototypes @ featb^T; emit pwB/pmB fragged + pws_neg ----------------
#define SBPITCH 136

__global__ __launch_bounds__(256, 2) void k_pside(
    const float* __restrict__ prototypes, const short* __restrict__ featbB,
    const float* __restrict__ beta_p,
    short* __restrict__ pwB, short* __restrict__ pmB, float* __restrict__ pws_neg)
{
    __shared__ char lds[35840];
    short* As = (short*)lds;
    short* Sb = (short*)lds;           // epilogue bounce (after last As use)

    const int t = threadIdx.x;
    const int w = t >> 6, lane = t & 63, l15 = lane & 15, l4 = lane >> 4;
    const int rowg = blockIdx.x >> 2, nc = blockIdx.x & 3;
    const float beta = *beta_p;

    float4v acc[4][4];
    #pragma unroll
    for (int a = 0; a < 4; ++a)
        #pragma unroll
        for (int b = 0; b < 4; ++b) acc[a][b] = (float4v){0.f, 0.f, 0.f, 0.f};

    const float* pbase = prototypes + (size_t)rowg * 128 * Dsz;

    for (int kc = 0; kc < 4; ++kc) {
        __syncthreads();
        #pragma unroll
        for (int j = 0; j < 8; ++j) {
            int idx = j * 1024 + t * 4;
            int r = idx >> 6, c = idx & 63;
            float4v v = *(const float4v*)(pbase + (size_t)r * Dsz + kc * 64 + c);
            int unit = r * 8 + ((c >> 3) ^ (r & 7));
            short4v s; s.x = f2bf(v.x); s.y = f2bf(v.y); s.z = f2bf(v.z); s.w = f2bf(v.w);
            *(short4v*)((char*)As + unit * 16 + (c & 7) * 2) = s;
        }
        __syncthreads();
        #pragma unroll
        for (int kk = 0; kk < 2; ++kk) {
            short8 af[4], bf[4];
            const int k8 = kk * 4 + l4;
            #pragma unroll
            for (int tm = 0; tm < 4; ++tm) {
                int m = (w & 1) * 64 + tm * 16 + l15;
                af[tm] = *(const short8*)&As[(m * 8 + (k8 ^ (m & 7))) * 8];
            }
            #pragma unroll
            for (int tn = 0; tn < 4; ++tn) {
                int fcb = nc * 8 + (w >> 1) * 4 + tn;
                bf[tn] = *(const short8*)&featbB[(size_t)fcb * 4096 +
                                                 (size_t)(kc * 2 + kk) * 512 + (size_t)lane * 8];
            }
            #pragma unroll
            for (int tm = 0; tm < 4; ++tm)
                #pragma unroll
                for (int tn = 0; tn < 4; ++tn)
                    acc[tm][tn] = __builtin_amdgcn_mfma_f32_16x16x32_bf16(af[tm], bf[tn], acc[tm][tn], 0, 0, 0);
        }
    }
    __syncthreads();
    #pragma unroll
    for (int tm = 0; tm < 4; ++tm)
        #pragma unroll
        for (int tn = 0; tn < 4; ++tn)
            #pragma unroll
            for (int r = 0; r < 4; ++r) {
                int row = (w & 1) * 64 + tm * 16 + l4 * 4 + r;
                int col = (w >> 1) * 64 + tn * 16 + l15;
                Sb[row * SBPITCH + col] = f2bf(acc[tm][tn][r]);
            }
    __syncthreads();
    #pragma unroll
    for (int rep = 0; rep < 8; ++rep) {
        int u = rep * 256 + t;
        int row = u >> 4, i = u & 15;
        short8 sv = *(const short8*)&Sb[row * SBPITCH + i * 8];
        short8 pwv, pmv;
        float sum = 0.f;
        #pragma unroll
        for (int e = 0; e < 8; ++e) {
            float pf = bf2f(sv[e]);
            float pp = fmaxf(pf, 0.f);
            float pw = pf * pp;
            pwv[e] = f2bf(pw);
            pmv[e] = f2bf(pp - 1.0f);
            sum += pw;
        }
        int p = rowg * 128 + row;
        int gcol = nc * 128 + i * 8;
        size_t fo = (size_t)(gcol >> 4) * 4096 + (size_t)(p >> 5) * 512 +
                    (size_t)((p & 31) + 32 * ((gcol >> 3) & 1)) * 8;
        *(short8*)&pwB[fo] = pwv;
        *(short8*)&pmB[fo] = pmv;
        #pragma unroll
        for (int mk = 1; mk < 16; mk <<= 1) sum += __shfl_xor(sum, mk, 64);
        if ((lane & 15) == 0) atomicAdd(&pws_neg[p], -beta * sum);
    }
}

// ---------------- k_main: fused, col-split, reg-pipelined, dbuf A12 ----------------
// 2048 blocks: rowg=bid>>1 (64 rows), ch=bid&1 (128 cols). Wave w: stage-1 rows 16w..16w+16,
// stage-2 col-tile ntile=ch*4+w (32 cols), m 0..63 via 2 MFMA A-frags.
__global__ __launch_bounds__(256, 3) void k_main(
    const float* __restrict__ x, const short* __restrict__ featbB,
    const short* __restrict__ pwB, const short* __restrict__ pmB,
    const float* __restrict__ pws_neg,
    const float* __restrict__ alpha_p, const float* __restrict__ beta_p,
    const float* __restrict__ theta_p, float* __restrict__ out)
{
    __shared__ short A12[4096];   // 2 bufs x [64 m][4 units][8], 8 KB

    const int t = threadIdx.x;
    const int w = t >> 6, lane = t & 63, l15 = lane & 15, l4 = lane >> 4;
    const int l31 = lane & 31, half = lane >> 5;
    const int rowg = blockIdx.x >> 1, ch = blockIdx.x & 1;
    const int ntile = ch * 4 + w;
    const float alpha = *alpha_p, beta = *beta_p, theta = *theta_p;
    const size_t row0 = (size_t)rowg * 64;

    // ---- x A-frags: 16 rows per wave, direct global -> regs ----
    short8 xreg[8];
    {
        const float* xr = x + (row0 + 16 * w + l15) * Dsz + l4 * 8;
        #pragma unroll
        for (int kk = 0; kk < 8; ++kk) {
            float4v v0 = *(const float4v*)(xr + kk * 32);
            float4v v1 = *(const float4v*)(xr + kk * 32 + 4);
            short8 s;
            s[0] = f2bf(v0.x); s[1] = f2bf(v0.y); s[2] = f2bf(v0.z); s[3] = f2bf(v0.w);
            s[4] = f2bf(v1.x); s[5] = f2bf(v1.y); s[6] = f2bf(v1.z); s[7] = f2bf(v1.w);
            xreg[kk] = s;
        }
    }

    float16v acc[2];
    #pragma unroll
    for (int a = 0; a < 2; ++a)
        #pragma unroll
        for (int e = 0; e < 16; ++e) acc[a][e] = 0.f;

    const int mbase = 16 * w + l4 * 4;
    const size_t lane8 = (size_t)lane * 8;

    short8 fbA[8], fbB[8], pA[2], pB[2];

    // prologue: load chunk 0 operands
    #pragma unroll
    for (int kk = 0; kk < 8; ++kk)
        fbA[kk] = *(const short8*)(featbB + kk * 512 + lane8);
    pA[0] = *(const short8*)(pwB + (size_t)ntile * 512 + lane8);
    pA[1] = *(const short8*)(pmB + (size_t)ntile * 512 + lane8);

    // chunk body: consumes cur, prefetches fc+1 into nxt
    auto body = [&](int fc, short8 (&fbc)[8], short8 (&fbn)[8],
                    short8 (&pc)[2], short8 (&pn)[2]) {
        const int buf = (fc & 1) << 11;
        const int fcn = (fc + 1) & 31;                 // wraps; avoids OOB prefetch
        const short* fbsrc = featbB + (size_t)fcn * 4096 + lane8;

        // stage-1: 8 MFMA, 2 independent chains
        float4v s0 = (float4v){0.f, 0.f, 0.f, 0.f};
        float4v s1 = (float4v){0.f, 0.f, 0.f, 0.f};
        #pragma unroll
        for (int kk = 0; kk < 8; kk += 2) {
            s0 = __builtin_amdgcn_mfma_f32_16x16x32_bf16(xreg[kk],     fbc[kk],     s0, 0, 0, 0);
            s1 = __builtin_amdgcn_mfma_f32_16x16x32_bf16(xreg[kk + 1], fbc[kk + 1], s1, 0, 0, 0);
        }

        // prefetch next: first half fb + p (pre-barrier issue point)
        #pragma unroll
        for (int kk = 0; kk < 4; ++kk) fbn[kk] = *(const short8*)(fbsrc + kk * 512);
        pn[0] = *(const short8*)(pwB + (size_t)fcn * 4096 + (size_t)ntile * 512 + lane8);
        pn[1] = *(const short8*)(pmB + (size_t)fcn * 4096 + (size_t)ntile * 512 + lane8);

        // epilogue: Tversky weights -> A12 dbuf
        #pragma unroll
        for (int r = 0; r < 4; ++r) {
            float sv = s0[r] + s1[r];
            float xp = fmaxf(sv, 0.f);
            float xw = sv * xp;
            int m = mbase + r;
            int swz = (m >> 2) & 3;
            A12[buf + (m * 4 + ((l15 >> 3) ^ swz)) * 8 + (l15 & 7)]       = f2bf(theta * xw + beta * xp);
            A12[buf + (m * 4 + ((2 | (l15 >> 3)) ^ swz)) * 8 + (l15 & 7)] = f2bf(alpha * xw);
        }
        __syncthreads();

        // prefetch next: second half fb (covered by stage-2 + next stage-1 front)
        #pragma unroll
        for (int kk = 4; kk < 8; ++kk) fbn[kk] = *(const short8*)(fbsrc + kk * 512);

        // stage-2: a-frags from A12, 4 MFMA 32x32x16
        #pragma unroll
        for (int mi = 0; mi < 2; ++mi) {
            int m = 32 * mi + l31;
            int swz = (m >> 2) & 3;
            short8 a1 = *(const short8*)&A12[buf + (m * 4 + (half ^ swz)) * 8];
            short8 a2 = *(const short8*)&A12[buf + (m * 4 + ((2 | half) ^ swz)) * 8];
            acc[mi] = __builtin_amdgcn_mfma_f32_32x32x16_bf16(a1, pc[0], acc[mi], 0, 0, 0);
            acc[mi] = __builtin_amdgcn_mfma_f32_32x32x16_bf16(a2, pc[1], acc[mi], 0, 0, 0);
        }
    };

    #pragma unroll 1
    for (int fc = 0; fc < 32; fc += 2) {
        body(fc,     fbA, fbB, pA, pB);
        body(fc + 1, fbB, fbA, pB, pA);
    }

    // ---- output: 32x32 C layout col=lane&31, row=(reg&3)+8*(reg>>2)+4*(lane>>5) ----
    {
        int col = ntile * 32 + l31;
        float pn_ = pws_neg[col];
        #pragma unroll
        for (int mi = 0; mi < 2; ++mi)
            #pragma unroll
            for (int rg = 0; rg < 16; ++rg) {
                size_t grow = row0 + 32 * mi + (rg & 3) + 8 * (rg >> 2) + 4 * half;
                out[grow * Psz + col] = acc[mi][rg] + pn_;
            }
    }
}

// ---------------- launcher ----------------
extern "C" void kernel_launch(void* const* d_in, const int* in_sizes, int n_in,
                              void* d_out, int out_size, void* d_ws, size_t ws_size,
                              hipStream_t stream) {
    const float* x          = (const float*)d_in[0];
    const float* features   = (const float*)d_in[1];
    const float* prototypes = (const float*)d_in[2];
    const float* alpha      = (const float*)d_in[3];
    const float* beta       = (const float*)d_in[4];
    const float* theta      = (const float*)d_in[5];
    float* out = (float*)d_out;

    // ws: featbB 256KB @0, pwB 256KB @262144, pmB 256KB @524288, pws_neg 1KB @786432
    char* ws = (char*)d_ws;
    short* featbB  = (short*)(ws);
    short* pwB     = (short*)(ws + 262144);
    short* pmB     = (short*)(ws + 524288);
    float* pws_neg = (float*)(ws + 786432);

    hipLaunchKernelGGL(k_prep,  dim3(64),   dim3(256), 0, stream, features, featbB, pws_neg);
    hipLaunchKernelGGL(k_pside, dim3(8),    dim3(256), 0, stream, prototypes, featbB, beta,
                       pwB, pmB, pws_neg);
    hipLaunchKernelGGL(k_main,  dim3(2048), dim3(256), 0, stream, x, featbB, pwB, pmB,
                       pws_neg, alpha, beta, theta, out);
}

// Round 8
// 193.798 us; speedup vs baseline: 1.1517x; 1.1517x over previous
//
#include <hip/hip_runtime.h>
#include <cstdint>
#include <cstddef>

#define Bsz 65536
#define Dsz 256
#define Fsz 512
#define Psz 256

typedef __attribute__((ext_vector_type(8))) short short8;
typedef __attribute__((ext_vector_type(4))) short short4v;
typedef __attribute__((ext_vector_type(4))) float float4v;
typedef __attribute__((ext_vector_type(16))) float float16v;

__device__ inline short f2bf(float f) {
    unsigned u = __builtin_bit_cast(unsigned, f);
    u = (u + 0x7FFFu + ((u >> 16) & 1u)) >> 16;   // RNE
    return (short)u;
}
__device__ inline float bf2f(short s) {
    unsigned u = ((unsigned)(unsigned short)s) << 16;
    return __builtin_bit_cast(float, u);
}

// Fragment-ordered layouts (addresses in shorts):
//   featbB[fc 0..31][kk 0..7][lane 0..63][j 0..7] : featb[f][d],
//       fc=f>>4, kk=d>>5, lane=(f&15)+16*((d>>3)&3), j=d&7
//   pwB/pmB[fc 0..31][ntile 0..7][lane 0..63][j 0..7] : pw[p][f],
//       fc=f>>4, ntile=p>>5, lane=(p&31)+32*((f>>3)&1), j=f&7

// ---------------- k_prep: features -> featbB (fragment order), zero pws_neg ----------------
__global__ void k_prep(const float* __restrict__ features, short* __restrict__ featbB,
                       float* __restrict__ pws_neg) {
    int idx = blockIdx.x * 256 + threadIdx.x;      // 64 blocks * 256 = 16384 = F*D/8
    int f = idx >> 5, d0 = (idx & 31) * 8;
    float4v v0 = *(const float4v*)(features + (size_t)f * Dsz + d0);
    float4v v1 = *(const float4v*)(features + (size_t)f * Dsz + d0 + 4);
    short8 s;
    s[0] = f2bf(v0.x); s[1] = f2bf(v0.y); s[2] = f2bf(v0.z); s[3] = f2bf(v0.w);
    s[4] = f2bf(v1.x); s[5] = f2bf(v1.y); s[6] = f2bf(v1.z); s[7] = f2bf(v1.w);
    int lane = (f & 15) + 16 * ((d0 >> 3) & 3);
    size_t o = (size_t)(f >> 4) * 4096 + (size_t)(d0 >> 5) * 512 + (size_t)lane * 8;
    *(short8*)&featbB[o] = s;
    if (idx < Psz) pws_neg[idx] = 0.f;
}

// ---------------- k_pside: pf = prototypes @ featb^T; emit pwB/pmB fragged + pws_neg ----------------
#define SBPITCH 136

__global__ __launch_bounds__(256, 2) void k_pside(
    const float* __restrict__ prototypes, const short* __restrict__ featbB,
    const float* __restrict__ beta_p,
    short* __restrict__ pwB, short* __restrict__ pmB, float* __restrict__ pws_neg)
{
    __shared__ char lds[35840];
    short* As = (short*)lds;
    short* Sb = (short*)lds;           // epilogue bounce (after last As use)

    const int t = threadIdx.x;
    const int w = t >> 6, lane = t & 63, l15 = lane & 15, l4 = lane >> 4;
    const int rowg = blockIdx.x >> 2, nc = blockIdx.x & 3;
    const float beta = *beta_p;

    float4v acc[4][4];
    #pragma unroll
    for (int a = 0; a < 4; ++a)
        #pragma unroll
        for (int b = 0; b < 4; ++b) acc[a][b] = (float4v){0.f, 0.f, 0.f, 0.f};

    const float* pbase = prototypes + (size_t)rowg * 128 * Dsz;

    for (int kc = 0; kc < 4; ++kc) {
        __syncthreads();
        #pragma unroll
        for (int j = 0; j < 8; ++j) {
            int idx = j * 1024 + t * 4;
            int r = idx >> 6, c = idx & 63;
            float4v v = *(const float4v*)(pbase + (size_t)r * Dsz + kc * 64 + c);
            int unit = r * 8 + ((c >> 3) ^ (r & 7));
            short4v s; s.x = f2bf(v.x); s.y = f2bf(v.y); s.z = f2bf(v.z); s.w = f2bf(v.w);
            *(short4v*)((char*)As + unit * 16 + (c & 7) * 2) = s;
        }
        __syncthreads();
        #pragma unroll
        for (int kk = 0; kk < 2; ++kk) {
            short8 af[4], bf[4];
            const int k8 = kk * 4 + l4;
            #pragma unroll
            for (int tm = 0; tm < 4; ++tm) {
                int m = (w & 1) * 64 + tm * 16 + l15;
                af[tm] = *(const short8*)&As[(m * 8 + (k8 ^ (m & 7))) * 8];
            }
            #pragma unroll
            for (int tn = 0; tn < 4; ++tn) {
                int fcb = nc * 8 + (w >> 1) * 4 + tn;
                bf[tn] = *(const short8*)&featbB[(size_t)fcb * 4096 +
                                                 (size_t)(kc * 2 + kk) * 512 + (size_t)lane * 8];
            }
            #pragma unroll
            for (int tm = 0; tm < 4; ++tm)
                #pragma unroll
                for (int tn = 0; tn < 4; ++tn)
                    acc[tm][tn] = __builtin_amdgcn_mfma_f32_16x16x32_bf16(af[tm], bf[tn], acc[tm][tn], 0, 0, 0);
        }
    }
    __syncthreads();
    #pragma unroll
    for (int tm = 0; tm < 4; ++tm)
        #pragma unroll
        for (int tn = 0; tn < 4; ++tn)
            #pragma unroll
            for (int r = 0; r < 4; ++r) {
                int row = (w & 1) * 64 + tm * 16 + l4 * 4 + r;
                int col = (w >> 1) * 64 + tn * 16 + l15;
                Sb[row * SBPITCH + col] = f2bf(acc[tm][tn][r]);
            }
    __syncthreads();
    #pragma unroll
    for (int rep = 0; rep < 8; ++rep) {
        int u = rep * 256 + t;
        int row = u >> 4, i = u & 15;
        short8 sv = *(const short8*)&Sb[row * SBPITCH + i * 8];
        short8 pwv, pmv;
        float sum = 0.f;
        #pragma unroll
        for (int e = 0; e < 8; ++e) {
            float pf = bf2f(sv[e]);
            float pp = fmaxf(pf, 0.f);
            float pw = pf * pp;
            pwv[e] = f2bf(pw);
            pmv[e] = f2bf(pp - 1.0f);
            sum += pw;
        }
        int p = rowg * 128 + row;
        int gcol = nc * 128 + i * 8;
        size_t fo = (size_t)(gcol >> 4) * 4096 + (size_t)(p >> 5) * 512 +
                    (size_t)((p & 31) + 32 * ((gcol >> 3) & 1)) * 8;
        *(short8*)&pwB[fo] = pwv;
        *(short8*)&pmB[fo] = pmv;
        #pragma unroll
        for (int mk = 1; mk < 16; mk <<= 1) sum += __shfl_xor(sum, mk, 64);
        if ((lane & 15) == 0) atomicAdd(&pws_neg[p], -beta * sum);
    }
}

// ---------------- k_main: round-6 shape + register-dbuf prefetch of fb/p ----------------
// 1024 blocks, 64 rows x 256 cols. F in 32 chunks of 16.
// Per chunk: stage-1 (16x16x32, fb frags from regs) -> A12 LDS dbuf -> barrier ->
//            stage-2 (32x32x16, p frags from regs). Next chunk's fb/p issued at body top.
__global__ __launch_bounds__(256, 2) void k_main(
    const float* __restrict__ x, const short* __restrict__ featbB,
    const short* __restrict__ pwB, const short* __restrict__ pmB,
    const float* __restrict__ pws_neg,
    const float* __restrict__ alpha_p, const float* __restrict__ beta_p,
    const float* __restrict__ theta_p, float* __restrict__ out)
{
    __shared__ short A12[4096];   // 2 bufs x [64 m][4 units][8], 8 KB

    const int t = threadIdx.x;
    const int w = t >> 6, lane = t & 63, l15 = lane & 15, l4 = lane >> 4;
    const int l31 = lane & 31, half = lane >> 5;
    const float alpha = *alpha_p, beta = *beta_p, theta = *theta_p;
    const size_t row0 = (size_t)blockIdx.x * 64;

    // ---- x A-frags: 16 rows per wave, direct global -> regs ----
    short8 xreg[8];
    {
        const float* xr = x + (row0 + 16 * w + l15) * Dsz + l4 * 8;
        #pragma unroll
        for (int kk = 0; kk < 8; ++kk) {
            float4v v0 = *(const float4v*)(xr + kk * 32);
            float4v v1 = *(const float4v*)(xr + kk * 32 + 4);
            short8 s;
            s[0] = f2bf(v0.x); s[1] = f2bf(v0.y); s[2] = f2bf(v0.z); s[3] = f2bf(v0.w);
            s[4] = f2bf(v1.x); s[5] = f2bf(v1.y); s[6] = f2bf(v1.z); s[7] = f2bf(v1.w);
            xreg[kk] = s;
        }
    }

    float16v acc[2][2];
    #pragma unroll
    for (int a = 0; a < 2; ++a)
        #pragma unroll
        for (int b = 0; b < 2; ++b)
            #pragma unroll
            for (int e = 0; e < 16; ++e) acc[a][b][e] = 0.f;

    const int mbase = 16 * w + l4 * 4;
    const size_t lane8 = (size_t)lane * 8;
    const size_t pwoff = (size_t)w * 1024 + lane8;

    short8 fbR[2][8];   // register dbuf: fb frags for cur/next chunk
    short8 pR[2][4];    // register dbuf: bw0,bw1,bm0,bm1

    // prologue: chunk-0 operands
    #pragma unroll
    for (int kk = 0; kk < 8; ++kk)
        fbR[0][kk] = *(const short8*)(featbB + kk * 512 + lane8);
    pR[0][0] = *(const short8*)(pwB + pwoff);
    pR[0][1] = *(const short8*)(pwB + pwoff + 512);
    pR[0][2] = *(const short8*)(pmB + pwoff);
    pR[0][3] = *(const short8*)(pmB + pwoff + 512);

    auto body = [&](int fc, int cur, int nxt) {
        const int buf = (fc & 1) << 11;
        const int fcn = (fc + 1) & 31;           // wraps at end (harmless extra loads)

        // ---- issue next-chunk loads first: a full chunk of slack before use ----
        const short* fbsrc = featbB + (size_t)fcn * 4096 + lane8;
        #pragma unroll
        for (int kk = 0; kk < 8; ++kk)
            fbR[nxt][kk] = *(const short8*)(fbsrc + kk * 512);
        pR[nxt][0] = *(const short8*)(pwB + (size_t)fcn * 4096 + pwoff);
        pR[nxt][1] = *(const short8*)(pwB + (size_t)fcn * 4096 + pwoff + 512);
        pR[nxt][2] = *(const short8*)(pmB + (size_t)fcn * 4096 + pwoff);
        pR[nxt][3] = *(const short8*)(pmB + (size_t)fcn * 4096 + pwoff + 512);

        // ---- stage-1: 8 MFMA, 2 independent chains, operands already in regs ----
        float4v s0 = (float4v){0.f, 0.f, 0.f, 0.f};
        float4v s1 = (float4v){0.f, 0.f, 0.f, 0.f};
        #pragma unroll
        for (int kk = 0; kk < 8; kk += 2) {
            s0 = __builtin_amdgcn_mfma_f32_16x16x32_bf16(xreg[kk],     fbR[cur][kk],     s0, 0, 0, 0);
            s1 = __builtin_amdgcn_mfma_f32_16x16x32_bf16(xreg[kk + 1], fbR[cur][kk + 1], s1, 0, 0, 0);
        }

        // ---- epilogue: Tversky weights -> A12 dbuf (XOR-unit swizzle) ----
        #pragma unroll
        for (int r = 0; r < 4; ++r) {
            float sv = s0[r] + s1[r];
            float xp = fmaxf(sv, 0.f);
            float xw = sv * xp;
            int m = mbase + r;
            int swz = (m >> 2) & 3;
            A12[buf + (m * 4 + ((l15 >> 3) ^ swz)) * 8 + (l15 & 7)]       = f2bf(theta * xw + beta * xp);
            A12[buf + (m * 4 + ((2 | (l15 >> 3)) ^ swz)) * 8 + (l15 & 7)] = f2bf(alpha * xw);
        }
        __syncthreads();

        // ---- stage-2: a-frags from A12, p-frags from regs, 8 MFMA 32x32x16 ----
        #pragma unroll
        for (int mi = 0; mi < 2; ++mi) {
            int m = 32 * mi + l31;
            int swz = (m >> 2) & 3;
            short8 a1 = *(const short8*)&A12[buf + (m * 4 + (half ^ swz)) * 8];
            short8 a2 = *(const short8*)&A12[buf + (m * 4 + ((2 | half) ^ swz)) * 8];
            acc[mi][0] = __builtin_amdgcn_mfma_f32_32x32x16_bf16(a1, pR[cur][0], acc[mi][0], 0, 0, 0);
            acc[mi][0] = __builtin_amdgcn_mfma_f32_32x32x16_bf16(a2, pR[cur][2], acc[mi][0], 0, 0, 0);
            acc[mi][1] = __builtin_amdgcn_mfma_f32_32x32x16_bf16(a1, pR[cur][1], acc[mi][1], 0, 0, 0);
            acc[mi][1] = __builtin_amdgcn_mfma_f32_32x32x16_bf16(a2, pR[cur][3], acc[mi][1], 0, 0, 0);
        }
    };

    #pragma unroll 1
    for (int fc = 0; fc < 32; fc += 2) {
        body(fc,     0, 1);
        body(fc + 1, 1, 0);
    }

    // ---- output: 32x32 C layout col=lane&31, row=(reg&3)+8*(reg>>2)+4*(lane>>5) ----
    #pragma unroll
    for (int ni = 0; ni < 2; ++ni) {
        int col = 64 * w + 32 * ni + l31;
        float pn_ = pws_neg[col];
        #pragma unroll
        for (int mi = 0; mi < 2; ++mi)
            #pragma unroll
            for (int rg = 0; rg < 16; ++rg) {
                size_t grow = row0 + 32 * mi + (rg & 3) + 8 * (rg >> 2) + 4 * half;
                out[grow * Psz + col] = acc[mi][ni][rg] + pn_;
            }
    }
}

// ---------------- launcher ----------------
extern "C" void kernel_launch(void* const* d_in, const int* in_sizes, int n_in,
                              void* d_out, int out_size, void* d_ws, size_t ws_size,
                              hipStream_t stream) {
    const float* x          = (const float*)d_in[0];
    const float* features   = (const float*)d_in[1];
    const float* prototypes = (const float*)d_in[2];
    const float* alpha      = (const float*)d_in[3];
    const float* beta       = (const float*)d_in[4];
    const float* theta      = (const float*)d_in[5];
    float* out = (float*)d_out;

    // ws: featbB 256KB @0, pwB 256KB @262144, pmB 256KB @524288, pws_neg 1KB @786432
    char* ws = (char*)d_ws;
    short* featbB  = (short*)(ws);
    short* pwB     = (short*)(ws + 262144);
    short* pmB     = (short*)(ws + 524288);
    float* pws_neg = (float*)(ws + 786432);

    hipLaunchKernelGGL(k_prep,  dim3(64),   dim3(256), 0, stream, features, featbB, pws_neg);
    hipLaunchKernelGGL(k_pside, dim3(8),    dim3(256), 0, stream, prototypes, featbB, beta,
                       pwB, pmB, pws_neg);
    hipLaunchKernelGGL(k_main,  dim3(1024), dim3(256), 0, stream, x, featbB, pwB, pmB,
                       pws_neg, alpha, beta, theta, out);
}